// Round 7
// baseline (123.683 us; speedup 1.0000x reference)
//
#include <hip/hip_runtime.h>
#include <hip/hip_bf16.h>
#include <stdint.h>

#define B_SZ 1024
#define M_SZ 209
#define MPAD 224            // padded M rows (14 * 16)
#define D_SZ 12288
#define KC   64             // split-K chunks; grid (64,16) = 1024 blocks = 4/CU
#define KCH  (D_SZ / KC)    // 192
#define BK   64             // K per staging iteration
#define NIT  (KCH / BK)     // 3
#define NB   16             // B splits
#define BT   64             // B rows per block
#define NCT  14             // 16-wide col tiles
#define SROW 224            // slab k-stride (bytes, fp8)
#define SLROW (KC * SROW)   // 14336

// ws byte offsets
#define CBF_OFF  0u                                   // c bf16 [224][12288]  (5.5 MB)
#define XXP_OFF  (MPAD * D_SZ * 2)                    // xx partials [B][KC] f32 (256 KB)
#define CCP_OFF  (XXP_OFF + B_SZ * KC * 4)            // cc halves [224][2] f32
#define SLAB_OFF (CCP_OFF + MPAD * 2 * 4)             // slab [B][KC][224] fp8 (14.7 MB)

typedef __attribute__((ext_vector_type(8))) short short8;
typedef __attribute__((ext_vector_type(4))) float floatx4;

__device__ __forceinline__ uint32_t pk2(float lo, float hi) {
    union { __hip_bfloat162 h; uint32_t u; } cv;
    cv.h = __float22bfloat162_rn(float2{lo, hi});
    return cv.u;
}

__device__ __forceinline__ uint8_t f2fp8(float v) {
    int p = __builtin_amdgcn_cvt_pk_fp8_f32(v, v, 0, false);
    return (uint8_t)(p & 0xff);
}

__device__ __forceinline__ void gload_lds16(const void* g, void* l) {
    __builtin_amdgcn_global_load_lds(
        (const __attribute__((address_space(1))) void*)g,
        (__attribute__((address_space(3))) void*)l, 16, 0, 0);
}

// ---------------------------------------------------------------------------
// prepass: c fp32 -> bf16 (padded to 224 rows, zeros) + ||c||^2 halves.
// 2 blocks per row (448 blocks), no atomics.
__global__ __launch_bounds__(256) void rbf_prep(
    const float* __restrict__ c, unsigned short* __restrict__ cbf,
    float* __restrict__ ccp)
{
    __shared__ float red[4];
    const int j = blockIdx.x >> 1, h = blockIdx.x & 1;
    const int t = threadIdx.x;
    const int base = h * (D_SZ / 2);
    unsigned short* dst = cbf + (size_t)j * D_SZ + base;
    float s = 0.f;
    if (j < M_SZ) {
        const float* src = c + (size_t)j * D_SZ + base;
        for (int i = t * 8; i < D_SZ / 2; i += 2048) {
            float4 v0 = *(const float4*)(src + i);
            float4 v1 = *(const float4*)(src + i + 4);
            s += v0.x*v0.x + v0.y*v0.y + v0.z*v0.z + v0.w*v0.w
               + v1.x*v1.x + v1.y*v1.y + v1.z*v1.z + v1.w*v1.w;
            uint4 w = { pk2(v0.x,v0.y), pk2(v0.z,v0.w), pk2(v1.x,v1.y), pk2(v1.z,v1.w) };
            *(uint4*)(dst + i) = w;
        }
    } else {
        uint4 zz = {0u, 0u, 0u, 0u};
        for (int i = t * 8; i < D_SZ / 2; i += 2048) *(uint4*)(dst + i) = zz;
    }
#pragma unroll
    for (int off = 32; off > 0; off >>= 1) s += __shfl_down(s, off);
    if ((t & 63) == 0) red[t >> 6] = s;
    __syncthreads();
    if (t == 0) ccp[j * 2 + h] = red[0] + red[1] + red[2] + red[3];
}

// ---------------------------------------------------------------------------
// main: split-K distance GEMM, 16x16x32 bf16 MFMA (R5 layout).
// c via global_load_lds DMA (XOR-swizzled LDS); all x prefetched in prologue;
// iter-0 c-DMA issued BEFORE the x-prefetch so both flights overlap.
__global__ __launch_bounds__(256, 4) void rbf_main(
    const float* __restrict__ x, const unsigned short* __restrict__ cbf,
    uint8_t* __restrict__ slab, float* __restrict__ xxp)
{
    __shared__ unsigned short sx[BT * BK];    //  8 KB
    __shared__ unsigned short sc[MPAD * BK];  // 28 KB   (36 KB total -> 4 blocks/CU)

    const int t    = threadIdx.x;
    const int k    = blockIdx.x;
    const int b    = blockIdx.y;
    const int wave = t >> 6, lane = t & 63;
    const int quad = lane >> 4, mrow = lane & 15;
    const int m3   = mrow & 7;

    floatx4 acc[NCT];
    const floatx4 z4 = {0.f, 0.f, 0.f, 0.f};
#pragma unroll
    for (int i = 0; i < NCT; ++i) acc[i] = z4;

    // c DMA mapping: lane L of round cr -> row cr*8 + L/8, LDS chunk L%8,
    // source chunk (L%8) ^ ((cr*8 + L/8)&7) = (L%8) ^ (L/8)
    const int lr8 = lane >> 3, lc8 = lane & 7;
    const unsigned short* cpb = cbf + (size_t)lr8 * D_SZ + (size_t)k * KCH
                              + (size_t)((lc8 ^ lr8) * 8);

    // ---- issue iter-0 c-DMA first (overlaps x-prefetch latency)
#pragma unroll
    for (int jj = 0; jj < 7; ++jj) {
        const int cr = wave * 7 + jj;
        gload_lds16(cpb + (size_t)cr * 8 * D_SZ, &sc[cr * 512]);
    }

    // ---- prologue: prefetch + convert ALL x for this block's k-slice
    const int r  = t >> 2;
    const int c0 = (t & 3) * 2;
    const float* xp = x + (size_t)(b * BT + r) * D_SZ + (size_t)k * KCH + (t & 3) * 16;

    uint4 xw[NIT][2];
    float sxx = 0.f;
#pragma unroll
    for (int it = 0; it < NIT; ++it) {
        float4 v0 = *(const float4*)(xp + it * BK + 0);
        float4 v1 = *(const float4*)(xp + it * BK + 4);
        float4 v2 = *(const float4*)(xp + it * BK + 8);
        float4 v3 = *(const float4*)(xp + it * BK + 12);
        sxx += v0.x*v0.x + v0.y*v0.y + v0.z*v0.z + v0.w*v0.w
             + v1.x*v1.x + v1.y*v1.y + v1.z*v1.z + v1.w*v1.w
             + v2.x*v2.x + v2.y*v2.y + v2.z*v2.z + v2.w*v2.w
             + v3.x*v3.x + v3.y*v3.y + v3.z*v3.z + v3.w*v3.w;
        xw[it][0] = make_uint4(pk2(v0.x,v0.y), pk2(v0.z,v0.w), pk2(v1.x,v1.y), pk2(v1.z,v1.w));
        xw[it][1] = make_uint4(pk2(v2.x,v2.y), pk2(v2.z,v2.w), pk2(v3.x,v3.y), pk2(v3.z,v3.w));
    }
    unsigned short* xw0 = &sx[r * BK + ((c0    ) ^ (r & 7)) * 8];
    unsigned short* xw1 = &sx[r * BK + ((c0 + 1) ^ (r & 7)) * 8];

    // MFMA fragment pointers (swizzle folded; row&7 == m3 for all rows)
    const unsigned short* ax0 = &sx[(wave * 16 + mrow) * BK + ((quad    ) ^ m3) * 8];
    const unsigned short* ax1 = &sx[(wave * 16 + mrow) * BK + ((quad + 4) ^ m3) * 8];
    const unsigned short* bx0 = &sc[mrow * BK + ((quad    ) ^ m3) * 8];
    const unsigned short* bx1 = &sc[mrow * BK + ((quad + 4) ^ m3) * 8];

#pragma unroll
    for (int it = 0; it < NIT; ++it) {
        // x stores for this iter (c-DMA for this iter already in flight)
        *(uint4*)xw0 = xw[it][0];
        *(uint4*)xw1 = xw[it][1];
        __syncthreads();

#pragma unroll
        for (int ks = 0; ks < 2; ++ks) {
            short8 a = *(const short8*)(ks ? ax1 : ax0);
            const unsigned short* bb = ks ? bx1 : bx0;
#pragma unroll
            for (int ct = 0; ct < NCT; ++ct) {
                short8 bf = *(const short8*)(bb + ct * 1024);
                acc[ct] = __builtin_amdgcn_mfma_f32_16x16x32_bf16(a, bf, acc[ct], 0, 0, 0);
            }
        }
        __syncthreads();

        if (it + 1 < NIT) {
            // issue next iter's c-DMA
#pragma unroll
            for (int jj = 0; jj < 7; ++jj) {
                const int cr = wave * 7 + jj;
                gload_lds16(cpb + (size_t)cr * 8 * D_SZ + (it + 1) * BK, &sc[cr * 512]);
            }
        }
    }

    // ---- slab write: [i][k][224] fp8. C/D layout: col=lane&15, row=quad*4+reg
    uint8_t* sd = slab + (size_t)k * SROW;
    const int gi0 = b * BT + wave * 16 + quad * 4;
#pragma unroll
    for (int ct = 0; ct < NCT; ++ct) {
        const int gj = ct * 16 + mrow;
#pragma unroll
        for (int rg = 0; rg < 4; ++rg)
            sd[(size_t)(gi0 + rg) * SLROW + gj] = f2fp8(acc[ct][rg]);
    }

    // ---- xx partials (no atomics)
    sxx += __shfl_down(sxx, 2);
    sxx += __shfl_down(sxx, 1);
    if ((t & 3) == 0) xxp[(size_t)(b * BT + r) * KC + k] = sxx;
}

// ---------------------------------------------------------------------------
// finalize: one block per row; thread t = column j. Reduce 64 fp8 k-partials,
// d2 = xx + cc - 2*dot, radial = exp(-sqrt/sig^2), dot with W, block-reduce.
__global__ __launch_bounds__(256) void rbf_fin(
    const uint8_t* __restrict__ slab, const float* __restrict__ xxp,
    const float* __restrict__ ccp, const float* __restrict__ sigma,
    const float* __restrict__ W, const float* __restrict__ bias,
    float* __restrict__ out)
{
    __shared__ float xsh;
    __shared__ float red[8];

    const int t = threadIdx.x;
    const int i = blockIdx.x;
    const int wave = t >> 6, lane = t & 63;

    // dot reduction over k (per kk, 224 threads read 224 contiguous bytes)
    float s = 0.f;
    if (t < SROW) {
        const uint8_t* sp = slab + (size_t)i * SLROW + t;
#pragma unroll 8
        for (int kk = 0; kk < KC; ++kk)
            s += __builtin_amdgcn_cvt_f32_fp8((int)sp[kk * SROW], 0);
    }

    // xx reduction (wave 0; KC == 64 lanes exactly)
    if (t < 64) {
        float xv = xxp[(size_t)i * KC + t];
#pragma unroll
        for (int off = 32; off > 0; off >>= 1) xv += __shfl_down(xv, off);
        if (t == 0) xsh = xv;
    }
    __syncthreads();

    float a0 = 0.f, a1 = 0.f;
    if (t < M_SZ) {
        const float ccj = ccp[t * 2] + ccp[t * 2 + 1];
        float d2 = fmaxf(xsh + ccj - 2.f * s, 0.f);
        float sg = sigma[t];
        float rad = __expf(-sqrtf(d2) / (sg * sg));
        a0 = rad * W[t];
        a1 = rad * W[M_SZ + t];
    }
#pragma unroll
    for (int off = 32; off > 0; off >>= 1) {
        a0 += __shfl_down(a0, off);
        a1 += __shfl_down(a1, off);
    }
    if (lane == 0) { red[wave * 2] = a0; red[wave * 2 + 1] = a1; }
    __syncthreads();
    if (t == 0) out[i * 2 + 0] = red[0] + red[2] + red[4] + red[6] + bias[0];
    if (t == 1) out[i * 2 + 1] = red[1] + red[3] + red[5] + red[7] + bias[1];
}

// ---------------------------------------------------------------------------
extern "C" void kernel_launch(void* const* d_in, const int* in_sizes, int n_in,
                              void* d_out, int out_size, void* d_ws, size_t ws_size,
                              hipStream_t stream)
{
    const float* x     = (const float*)d_in[0];
    const float* c     = (const float*)d_in[1];
    const float* sigma = (const float*)d_in[2];
    const float* W     = (const float*)d_in[3];
    const float* bias  = (const float*)d_in[4];
    float* out = (float*)d_out;

    char* ws = (char*)d_ws;
    unsigned short* cbf  = (unsigned short*)(ws + CBF_OFF);
    float*          xxp  = (float*)(ws + XXP_OFF);
    float*          ccp  = (float*)(ws + CCP_OFF);
    uint8_t*        slab = (uint8_t*)(ws + SLAB_OFF);

    rbf_prep<<<MPAD * 2, 256, 0, stream>>>(c, cbf, ccp);
    rbf_main<<<dim3(KC, NB), 256, 0, stream>>>(x, cbf, slab, xxp);
    rbf_fin<<<B_SZ, 256, 0, stream>>>(slab, xxp, ccp, sigma, W, bias, out);
}

// Round 8
// 111.741 us; speedup vs baseline: 1.1069x; 1.1069x over previous
//
#include <hip/hip_runtime.h>
#include <hip/hip_bf16.h>
#include <stdint.h>

#define B_SZ 1024
#define M_SZ 209
#define MPAD 224            // padded M rows (14 * 16)
#define D_SZ 12288
#define KC   48             // split-K chunks; grid (48,16) = 768 blocks = 3/CU
#define KCH  256            // K elems per chunk (D/KC)
#define BK   128            // K per staging iteration (bytes == elems, fp8)
#define NIT  (KCH / BK)     // 2
#define NB   16
#define BT   64
#define NCT  14             // 16-wide col tiles
#define SROW 224            // slab k-stride (bf16 elems)
#define SLROW (KC * SROW)   // 10752

// ws byte offsets
#define CBF_OFF  0u                                   // c fp8 [224][12288]  (2.75 MB)
#define XXP_OFF  (MPAD * D_SZ)                        // xx partials [B][KC] f32
#define CCP_OFF  (XXP_OFF + B_SZ * KC * 4)            // cc halves [224][2] f32
#define SLAB_OFF (CCP_OFF + MPAD * 2 * 4)             // slab [B][KC][224] bf16 (22 MB)

typedef __attribute__((ext_vector_type(8))) short short8;
typedef __attribute__((ext_vector_type(4))) float floatx4;

__device__ __forceinline__ uint32_t pk8x4(const float4& v) {
    int d = __builtin_amdgcn_cvt_pk_fp8_f32(v.x, v.y, 0, false);
    d     = __builtin_amdgcn_cvt_pk_fp8_f32(v.z, v.w, d, true);
    return (uint32_t)d;
}

__device__ __forceinline__ float bfbits2f(unsigned short u) {
    union { uint32_t u; float f; } cv;
    cv.u = ((uint32_t)u) << 16;
    return cv.f;
}

__device__ __forceinline__ void gload_lds16(const void* g, void* l) {
    __builtin_amdgcn_global_load_lds(
        (const __attribute__((address_space(1))) void*)g,
        (__attribute__((address_space(3))) void*)l, 16, 0, 0);
}

// ---------------------------------------------------------------------------
// prepass: c fp32 -> fp8 e4m3 (padded to 224 rows, zeros) + ||c||^2 halves.
__global__ __launch_bounds__(256) void rbf_prep(
    const float* __restrict__ c, uint8_t* __restrict__ cf8,
    float* __restrict__ ccp)
{
    __shared__ float red[4];
    const int j = blockIdx.x >> 1, h = blockIdx.x & 1;
    const int t = threadIdx.x;
    const int base = h * (D_SZ / 2);
    uint8_t* dst = cf8 + (size_t)j * D_SZ + base;
    float s = 0.f;
    if (j < M_SZ) {
        const float* src = c + (size_t)j * D_SZ + base;
        for (int i = t * 8; i < D_SZ / 2; i += 2048) {
            float4 v0 = *(const float4*)(src + i);
            float4 v1 = *(const float4*)(src + i + 4);
            s += v0.x*v0.x + v0.y*v0.y + v0.z*v0.z + v0.w*v0.w
               + v1.x*v1.x + v1.y*v1.y + v1.z*v1.z + v1.w*v1.w;
            uint2 w = { pk8x4(v0), pk8x4(v1) };
            *(uint2*)(dst + i) = w;
        }
    } else {
        uint2 zz = {0u, 0u};
        for (int i = t * 8; i < D_SZ / 2; i += 2048) *(uint2*)(dst + i) = zz;
    }
#pragma unroll
    for (int off = 32; off > 0; off >>= 1) s += __shfl_down(s, off);
    if ((t & 63) == 0) red[t >> 6] = s;
    __syncthreads();
    if (t == 0) ccp[j * 2 + h] = red[0] + red[1] + red[2] + red[3];
}

// ---------------------------------------------------------------------------
// main: split-K distance GEMM, 16x16x32 fp8_fp8 MFMA.
// A (x rows) lives in registers: each lane prefetches its own 64 floats,
// converts to 8 fp8-longs. B (c) staged via global_load_lds DMA into a
// 16B-chunk XOR-swizzled LDS tile (128 B rows, no sx buffer at all).
__global__ __launch_bounds__(256, 3) void rbf_main(
    const float* __restrict__ x, const uint8_t* __restrict__ cf8,
    __hip_bfloat16* __restrict__ slab, float* __restrict__ xxp)
{
    __shared__ uint8_t sc[MPAD * BK];   // 28 KB

    const int t    = threadIdx.x;
    const int k    = blockIdx.x;
    const int b    = blockIdx.y;
    const int wave = t >> 6, lane = t & 63;
    const int quad = lane >> 4, mrow = lane & 15;
    const int qh = quad >> 1, ql = quad & 1;
    const int s2 = (mrow >> 1) & 7;

    floatx4 acc[NCT];
    const floatx4 z4 = {0.f, 0.f, 0.f, 0.f};
#pragma unroll
    for (int i = 0; i < NCT; ++i) acc[i] = z4;

    // ---- c-DMA lane source pointers.
    // Round cr (8 rows, 1 KB): lane L -> row cr*8 + (L>>3), LDS chunk16 L&7.
    // Swizzle chunk' = chunk ^ ((row>>1)&7) => src chunk = (L&7)^((cr*4 + (L>>4))&7)
    //   = (L&7)^(L>>4)        for even cr
    //   = (L&7)^(L>>4)^4      for odd  cr
    const int oE = (((lane & 7) ^ (lane >> 4)) & 7) * 16;
    const int oO = ((((lane & 7) ^ (lane >> 4)) ^ 4) & 7) * 16;
    const uint8_t* cpbE = cf8 + (size_t)(lane >> 3) * D_SZ + (size_t)k * KCH + oE;
    const uint8_t* cpbO = cf8 + (size_t)(lane >> 3) * D_SZ + (size_t)k * KCH + oO;

    // ---- peel: issue iter-0 c-DMA before the x-prefetch (flights overlap)
#pragma unroll
    for (int jj = 0; jj < 7; ++jj) {
        const int cr = wave * 7 + jj;
        const uint8_t* p = ((cr & 1) ? cpbO : cpbE) + (size_t)cr * 8 * D_SZ;
        gload_lds16(p, &sc[cr * 1024]);
    }

    // ---- x prefetch: this lane's row, 64 floats -> 8 fp8-longs (A-operands)
    // chunk ci (it = ci>>2, ks = ci&3): floats at it*128 + ks*32 + quad*8
    const float* xr = x + (size_t)(b * BT + wave * 16 + mrow) * D_SZ
                    + (size_t)k * KCH + quad * 8;
    long xa[8];
    float sxx = 0.f;
#pragma unroll
    for (int half = 0; half < 2; ++half) {
        float4 fa[4], fb[4];
#pragma unroll
        for (int u = 0; u < 4; ++u) {
            const int ci = half * 4 + u;
            const int fo = (ci >> 2) * 128 + (ci & 3) * 32;
            fa[u] = *(const float4*)(xr + fo);
            fb[u] = *(const float4*)(xr + fo + 4);
        }
#pragma unroll
        for (int u = 0; u < 4; ++u) {
            sxx += fa[u].x*fa[u].x + fa[u].y*fa[u].y + fa[u].z*fa[u].z + fa[u].w*fa[u].w
                 + fb[u].x*fb[u].x + fb[u].y*fb[u].y + fb[u].z*fb[u].z + fb[u].w*fb[u].w;
            const uint32_t lo = pk8x4(fa[u]);
            const uint32_t hi = pk8x4(fb[u]);
            xa[half * 4 + u] = (long)(((uint64_t)hi << 32) | lo);
        }
    }

    // ---- B fragment offsets: row n = ct*16 + mrow (128 B rows);
    // k-step ks: chunk16 = ks*2 + qh, swizzled by s2; half ql.
    int boff[4];
#pragma unroll
    for (int ks = 0; ks < 4; ++ks)
        boff[ks] = (((ks * 2 + qh) ^ s2) * 16) + ql * 8;
    const uint8_t* bbase = &sc[mrow * BK];

    for (int it = 0; it < NIT; ++it) {
        __syncthreads();   // DMA(it) complete
#pragma unroll
        for (int ks = 0; ks < 4; ++ks) {
            const long a = xa[it * 4 + ks];
#pragma unroll
            for (int ct = 0; ct < NCT; ++ct) {
                const long bv = *(const long*)(bbase + ct * 16 * BK + boff[ks]);
                acc[ct] = __builtin_amdgcn_mfma_f32_16x16x32_fp8_fp8(a, bv, acc[ct], 0, 0, 0);
            }
        }
        __syncthreads();   // all reads of sc done
        if (it + 1 < NIT) {
#pragma unroll
            for (int jj = 0; jj < 7; ++jj) {
                const int cr = wave * 7 + jj;
                const uint8_t* p = ((cr & 1) ? cpbO : cpbE)
                                 + (size_t)cr * 8 * D_SZ + (it + 1) * BK;
                gload_lds16(p, &sc[cr * 1024]);
            }
        }
    }

    // ---- slab write: [i][k][224] bf16. C/D: col=lane&15, row=quad*4+reg
    __hip_bfloat16* sd = slab + (size_t)k * SROW;
    const int gi0 = b * BT + wave * 16 + quad * 4;
#pragma unroll
    for (int ct = 0; ct < NCT; ++ct) {
        const int gj = ct * 16 + mrow;
#pragma unroll
        for (int rg = 0; rg < 4; ++rg)
            sd[(size_t)(gi0 + rg) * SLROW + gj] = __float2bfloat16(acc[ct][rg]);
    }

    // ---- xx partials: reduce over quads (lanes m, m+16, m+32, m+48)
    sxx += __shfl_down(sxx, 32);
    sxx += __shfl_down(sxx, 16);
    if (lane < 16)
        xxp[(size_t)(b * BT + wave * 16 + lane) * KC + k] = sxx;
}

// ---------------------------------------------------------------------------
// finalize (R5-proven): one block per row; octet k-reduction of bf16 slab,
// then radial + W epilogue.
__global__ __launch_bounds__(256) void rbf_fin(
    const __hip_bfloat16* __restrict__ slab, const float* __restrict__ xxp,
    const float* __restrict__ ccp, const float* __restrict__ sigma,
    const float* __restrict__ W, const float* __restrict__ bias,
    float* __restrict__ out)
{
    __shared__ float jpart[MPAD * 9];
    __shared__ float jtot[MPAD];
    __shared__ float xsh;

    const int t = threadIdx.x;
    const int i = blockIdx.x;

    if (t < 64) {
        float xv = (t < KC) ? xxp[(size_t)i * KC + t] : 0.f;
#pragma unroll
        for (int off = 32; off > 0; off >>= 1) xv += __shfl_down(xv, off);
        if (t == 0) xsh = xv;
    }

    const int o = t % 28, g = t / 28;
    if (t < 252) {
        const unsigned short* sp = (const unsigned short*)slab
                                 + (size_t)i * SLROW + o * 8;
        float s8[8] = {0.f,0.f,0.f,0.f,0.f,0.f,0.f,0.f};
        for (int kk = g; kk < KC; kk += 9) {
            short8 v = *(const short8*)(sp + kk * SROW);
#pragma unroll
            for (int e = 0; e < 8; ++e) s8[e] += bfbits2f((unsigned short)v[e]);
        }
#pragma unroll
        for (int e = 0; e < 8; ++e) jpart[(o * 8 + e) * 9 + g] = s8[e];
    }
    __syncthreads();

    if (t < MPAD) {
        float d = 0.f;
#pragma unroll
        for (int g2 = 0; g2 < 9; ++g2) d += jpart[t * 9 + g2];
        jtot[t] = d;
    }
    __syncthreads();

    if (t < 64) {
        const float xxi = xsh;
        float a0 = 0.f, a1 = 0.f;
        for (int j = t; j < M_SZ; j += 64) {
            const float ccj = ccp[j * 2] + ccp[j * 2 + 1];
            float d2 = fmaxf(xxi + ccj - 2.f * jtot[j], 0.f);
            float sg = sigma[j];
            float rad = __expf(-sqrtf(d2) / (sg * sg));
            a0 += rad * W[j];
            a1 += rad * W[M_SZ + j];
        }
#pragma unroll
        for (int off = 32; off > 0; off >>= 1) {
            a0 += __shfl_down(a0, off);
            a1 += __shfl_down(a1, off);
        }
        if (t == 0) {
            out[i * 2 + 0] = a0 + bias[0];
            out[i * 2 + 1] = a1 + bias[1];
        }
    }
}

// ---------------------------------------------------------------------------
extern "C" void kernel_launch(void* const* d_in, const int* in_sizes, int n_in,
                              void* d_out, int out_size, void* d_ws, size_t ws_size,
                              hipStream_t stream)
{
    const float* x     = (const float*)d_in[0];
    const float* c     = (const float*)d_in[1];
    const float* sigma = (const float*)d_in[2];
    const float* W     = (const float*)d_in[3];
    const float* bias  = (const float*)d_in[4];
    float* out = (float*)d_out;

    char* ws = (char*)d_ws;
    uint8_t*        cf8  = (uint8_t*)(ws + CBF_OFF);
    float*          xxp  = (float*)(ws + XXP_OFF);
    float*          ccp  = (float*)(ws + CCP_OFF);
    __hip_bfloat16* slab = (__hip_bfloat16*)(ws + SLAB_OFF);

    rbf_prep<<<MPAD * 2, 256, 0, stream>>>(c, cf8, ccp);
    rbf_main<<<dim3(KC, NB), 256, 0, stream>>>(x, cf8, slab, xxp);
    rbf_fin<<<B_SZ, 256, 0, stream>>>(slab, xxp, ccp, sigma, W, bias, out);
}

// Round 9
// 109.995 us; speedup vs baseline: 1.1244x; 1.0159x over previous
//
#include <hip/hip_runtime.h>
#include <hip/hip_bf16.h>
#include <stdint.h>

#define B_SZ 1024
#define M_SZ 209
#define MPAD 224            // padded M rows (14 * 16)
#define D_SZ 12288
#define KC   32             // split-K chunks
#define KCH  384            // K elems per chunk (D/KC)
#define BK   128            // K per staging iteration (fp8 bytes == elems)
#define NIT  (KCH / BK)     // 3
#define NB   32             // B splits -> grid (32,32) = 1024 blocks = 4/CU
#define BT   32             // B rows per block
#define NCT  7              // 16-wide col tiles per wave (ct-half)
#define SROW 224            // slab k-stride (bf16 elems)
#define SLROW (KC * SROW)   // 7168

// ws byte offsets
#define CBF_OFF  0u                                   // c fp8 [224][12288] (2.75 MB)
#define XXP_OFF  (MPAD * D_SZ)                        // xx partials [B][KC] f32 (128 KB)
#define CCP_OFF  (XXP_OFF + B_SZ * KC * 4)            // cc halves [224][2] f32
#define SLAB_OFF (CCP_OFF + MPAD * 2 * 4)             // slab [B][KC][224] bf16 (14.7 MB)

typedef __attribute__((ext_vector_type(8))) short short8;
typedef __attribute__((ext_vector_type(4))) float floatx4;

__device__ __forceinline__ uint32_t pk8x4(const float4& v) {
    int d = __builtin_amdgcn_cvt_pk_fp8_f32(v.x, v.y, 0, false);
    d     = __builtin_amdgcn_cvt_pk_fp8_f32(v.z, v.w, d, true);
    return (uint32_t)d;
}

__device__ __forceinline__ float bfbits2f(unsigned short u) {
    union { uint32_t u; float f; } cv;
    cv.u = ((uint32_t)u) << 16;
    return cv.f;
}

__device__ __forceinline__ void gload_lds16(const void* g, void* l) {
    __builtin_amdgcn_global_load_lds(
        (const __attribute__((address_space(1))) void*)g,
        (__attribute__((address_space(3))) void*)l, 16, 0, 0);
}

// ---------------------------------------------------------------------------
// prepass: c fp32 -> fp8 e4m3 (padded to 224 rows, zeros) + ||c||^2 halves.
__global__ __launch_bounds__(256) void rbf_prep(
    const float* __restrict__ c, uint8_t* __restrict__ cf8,
    float* __restrict__ ccp)
{
    __shared__ float red[4];
    const int j = blockIdx.x >> 1, h = blockIdx.x & 1;
    const int t = threadIdx.x;
    const int base = h * (D_SZ / 2);
    uint8_t* dst = cf8 + (size_t)j * D_SZ + base;
    float s = 0.f;
    if (j < M_SZ) {
        const float* src = c + (size_t)j * D_SZ + base;
        for (int i = t * 8; i < D_SZ / 2; i += 2048) {
            float4 v0 = *(const float4*)(src + i);
            float4 v1 = *(const float4*)(src + i + 4);
            s += v0.x*v0.x + v0.y*v0.y + v0.z*v0.z + v0.w*v0.w
               + v1.x*v1.x + v1.y*v1.y + v1.z*v1.z + v1.w*v1.w;
            uint2 w = { pk8x4(v0), pk8x4(v1) };
            *(uint2*)(dst + i) = w;
        }
    } else {
        uint2 zz = {0u, 0u};
        for (int i = t * 8; i < D_SZ / 2; i += 2048) *(uint2*)(dst + i) = zz;
    }
#pragma unroll
    for (int off = 32; off > 0; off >>= 1) s += __shfl_down(s, off);
    if ((t & 63) == 0) red[t >> 6] = s;
    __syncthreads();
    if (t == 0) ccp[j * 2 + h] = red[0] + red[1] + red[2] + red[3];
}

// ---------------------------------------------------------------------------
// main: split-K distance GEMM, 16x16x32 fp8_fp8 MFMA, BT=32, 4 blocks/CU.
// Wave roles: row-tile = w&1, ct-half = w>>1. c staged via global_load_lds
// DMA; x staged through a 4 KB fp8 sx tile (converted in-register, all NIT
// slabs prefetched in the prologue).
__global__ __launch_bounds__(256, 4) void rbf_main(
    const float* __restrict__ x, const uint8_t* __restrict__ cf8,
    __hip_bfloat16* __restrict__ slab, float* __restrict__ xxp)
{
    __shared__ uint8_t sx[BT * BK];     //  4 KB
    __shared__ uint8_t sc[MPAD * BK];   // 28 KB  (32 KB total -> 4 blocks/CU)

    const int t    = threadIdx.x;
    const int k    = blockIdx.x;
    const int b    = blockIdx.y;
    const int wave = t >> 6, lane = t & 63;
    const int quad = lane >> 4, mrow = lane & 15;
    const int qh = quad >> 1, ql = quad & 1;
    const int s2 = (mrow >> 1) & 7;
    const int rt  = wave & 1;           // row-tile (16 rows)
    const int cth = wave >> 1;          // ct-half (7 tiles)

    floatx4 acc[NCT];
    const floatx4 z4 = {0.f, 0.f, 0.f, 0.f};
#pragma unroll
    for (int i = 0; i < NCT; ++i) acc[i] = z4;

    // ---- c-DMA lane source pointers (R8-verified mapping).
    // Round cr: lane L -> row cr*8 + (L>>3), LDS chunk16 L&7,
    // src chunk = (L&7) ^ ((cr*4 + (L>>4)) & 7)  -> even cr / odd cr variants
    const int oE = (((lane & 7) ^ (lane >> 4)) & 7) * 16;
    const int oO = ((((lane & 7) ^ (lane >> 4)) ^ 4) & 7) * 16;
    const uint8_t* cpbE = cf8 + (size_t)(lane >> 3) * D_SZ + (size_t)k * KCH + oE;
    const uint8_t* cpbO = cf8 + (size_t)(lane >> 3) * D_SZ + (size_t)k * KCH + oO;

    // ---- peel: issue iter-0 c-DMA before x-prefetch (flights overlap)
#pragma unroll
    for (int jj = 0; jj < 7; ++jj) {
        const int cr = wave * 7 + jj;
        const uint8_t* p = ((cr & 1) ? cpbO : cpbE) + (size_t)cr * 8 * D_SZ;
        gload_lds16(p, &sc[cr * 1024]);
    }

    // ---- x prologue: 8 threads/row, 16 floats each per iter -> fp8 uint4
    const int xr = t >> 3;              // staging row 0..31
    const int xc = t & 7;               // 16-float column group
    const float* xp = x + (size_t)(b * BT + xr) * D_SZ + (size_t)k * KCH + xc * 16;

    uint4 xw[NIT];
    float sxx = 0.f;
#pragma unroll
    for (int it = 0; it < NIT; ++it) {
        float4 v0 = *(const float4*)(xp + it * BK + 0);
        float4 v1 = *(const float4*)(xp + it * BK + 4);
        float4 v2 = *(const float4*)(xp + it * BK + 8);
        float4 v3 = *(const float4*)(xp + it * BK + 12);
        sxx += v0.x*v0.x + v0.y*v0.y + v0.z*v0.z + v0.w*v0.w
             + v1.x*v1.x + v1.y*v1.y + v1.z*v1.z + v1.w*v1.w
             + v2.x*v2.x + v2.y*v2.y + v2.z*v2.z + v2.w*v2.w
             + v3.x*v3.x + v3.y*v3.y + v3.z*v3.z + v3.w*v3.w;
        xw[it] = make_uint4(pk8x4(v0), pk8x4(v1), pk8x4(v2), pk8x4(v3));
    }
    // sx dest: row xr, chunk16 = xc ^ ((xr>>1)&7)
    uint8_t* sxw = &sx[xr * BK + ((xc ^ ((xr >> 1) & 7)) & 7) * 16];

    // ---- fragment offsets (shared by A and B; rows have same s2 law)
    int boff[4];
#pragma unroll
    for (int ks = 0; ks < 4; ++ks)
        boff[ks] = (((ks * 2 + qh) ^ s2) & 7) * 16 + ql * 8;
    const uint8_t* abase = &sx[(rt * 16 + mrow) * BK];
    const uint8_t* bbase = &sc[(cth * 7 * 16 + mrow) * BK];

    for (int it = 0; it < NIT; ++it) {
        *(uint4*)sxw = xw[it];
        __syncthreads();   // DMA(it) + x-writes complete
#pragma unroll
        for (int ks = 0; ks < 4; ++ks) {
            const long a = *(const long*)(abase + boff[ks]);
#pragma unroll
            for (int ct = 0; ct < NCT; ++ct) {
                const long bv = *(const long*)(bbase + ct * 16 * BK + boff[ks]);
                acc[ct] = __builtin_amdgcn_mfma_f32_16x16x32_fp8_fp8(a, bv, acc[ct], 0, 0, 0);
            }
        }
        __syncthreads();   // all reads of sx/sc done
        if (it + 1 < NIT) {
#pragma unroll
            for (int jj = 0; jj < 7; ++jj) {
                const int cr = wave * 7 + jj;
                const uint8_t* p = ((cr & 1) ? cpbO : cpbE)
                                 + (size_t)cr * 8 * D_SZ + (it + 1) * BK;
                gload_lds16(p, &sc[cr * 1024]);
            }
        }
    }

    // ---- slab write: [i][k][224] bf16. C/D: col=lane&15, row=quad*4+reg
    __hip_bfloat16* sd = slab + (size_t)k * SROW;
    const int gi0 = b * BT + rt * 16 + quad * 4;
#pragma unroll
    for (int ct = 0; ct < NCT; ++ct) {
        const int gj = (cth * 7 + ct) * 16 + mrow;
#pragma unroll
        for (int rg = 0; rg < 4; ++rg)
            sd[(size_t)(gi0 + rg) * SLROW + gj] = __float2bfloat16(acc[ct][rg]);
    }

    // ---- xx partials: 8 staging threads per row -> 1 write (no atomics)
    sxx += __shfl_down(sxx, 4);
    sxx += __shfl_down(sxx, 2);
    sxx += __shfl_down(sxx, 1);
    if ((t & 7) == 0) xxp[(size_t)(b * BT + xr) * KC + k] = sxx;
}

// ---------------------------------------------------------------------------
// finalize: one block per row; octet k-reduction of bf16 slab, then radial
// + W epilogue.
__global__ __launch_bounds__(256) void rbf_fin(
    const __hip_bfloat16* __restrict__ slab, const float* __restrict__ xxp,
    const float* __restrict__ ccp, const float* __restrict__ sigma,
    const float* __restrict__ W, const float* __restrict__ bias,
    float* __restrict__ out)
{
    __shared__ float jpart[MPAD * 9];
    __shared__ float jtot[MPAD];
    __shared__ float xsh;

    const int t = threadIdx.x;
    const int i = blockIdx.x;

    if (t < 64) {
        float xv = (t < KC) ? xxp[(size_t)i * KC + t] : 0.f;
#pragma unroll
        for (int off = 32; off > 0; off >>= 1) xv += __shfl_down(xv, off);
        if (t == 0) xsh = xv;
    }

    const int o = t % 28, g = t / 28;
    if (t < 252) {
        const unsigned short* sp = (const unsigned short*)slab
                                 + (size_t)i * SLROW + o * 8;
        float s8[8] = {0.f,0.f,0.f,0.f,0.f,0.f,0.f,0.f};
        for (int kk = g; kk < KC; kk += 9) {
            short8 v = *(const short8*)(sp + kk * SROW);
#pragma unroll
            for (int e = 0; e < 8; ++e) s8[e] += bfbits2f((unsigned short)v[e]);
        }
#pragma unroll
        for (int e = 0; e < 8; ++e) jpart[(o * 8 + e) * 9 + g] = s8[e];
    }
    __syncthreads();

    if (t < MPAD) {
        float d = 0.f;
#pragma unroll
        for (int g2 = 0; g2 < 9; ++g2) d += jpart[t * 9 + g2];
        jtot[t] = d;
    }
    __syncthreads();

    if (t < 64) {
        const float xxi = xsh;
        float a0 = 0.f, a1 = 0.f;
        for (int j = t; j < M_SZ; j += 64) {
            const float ccj = ccp[j * 2] + ccp[j * 2 + 1];
            float d2 = fmaxf(xxi + ccj - 2.f * jtot[j], 0.f);
            float sg = sigma[j];
            float rad = __expf(-sqrtf(d2) / (sg * sg));
            a0 += rad * W[j];
            a1 += rad * W[M_SZ + j];
        }
#pragma unroll
        for (int off = 32; off > 0; off >>= 1) {
            a0 += __shfl_down(a0, off);
            a1 += __shfl_down(a1, off);
        }
        if (t == 0) {
            out[i * 2 + 0] = a0 + bias[0];
            out[i * 2 + 1] = a1 + bias[1];
        }
    }
}

// ---------------------------------------------------------------------------
extern "C" void kernel_launch(void* const* d_in, const int* in_sizes, int n_in,
                              void* d_out, int out_size, void* d_ws, size_t ws_size,
                              hipStream_t stream)
{
    const float* x     = (const float*)d_in[0];
    const float* c     = (const float*)d_in[1];
    const float* sigma = (const float*)d_in[2];
    const float* W     = (const float*)d_in[3];
    const float* bias  = (const float*)d_in[4];
    float* out = (float*)d_out;

    char* ws = (char*)d_ws;
    uint8_t*        cf8  = (uint8_t*)(ws + CBF_OFF);
    float*          xxp  = (float*)(ws + XXP_OFF);
    float*          ccp  = (float*)(ws + CCP_OFF);
    __hip_bfloat16* slab = (__hip_bfloat16*)(ws + SLAB_OFF);

    rbf_prep<<<MPAD * 2, 256, 0, stream>>>(c, cf8, ccp);
    rbf_main<<<dim3(KC, NB), 256, 0, stream>>>(x, cf8, slab, xxp);
    rbf_fin<<<B_SZ, 256, 0, stream>>>(slab, xxp, ccp, sigma, W, bias, out);
}